// Round 1
// baseline (412.092 us; speedup 1.0000x reference)
//
#include <hip/hip_runtime.h>
#include <hip/hip_bf16.h>
#include <cstdint>

#define HW_H 128
#define HW_W 128
#define MASK_ELEMS (HW_H * HW_W)

#define BM 32
#define BK 64
#define TT 160
#define KSPLIT 14

typedef __attribute__((ext_vector_type(8))) unsigned short ushortx8;

__device__ __forceinline__ float bf2f(unsigned short u) {
    union { unsigned int i; float f; } c;
    c.i = ((unsigned int)u) << 16;
    return c.f;
}

__device__ __forceinline__ unsigned short f2bf(float f) {
    union { float f; unsigned int i; } c;
    c.f = f;
    unsigned int r = c.i + 0x7FFFu + ((c.i >> 16) & 1u);  // RNE
    return (unsigned short)(r >> 16);
}

// Bilinear tap from an LDS-resident [128][128] mask. p = {x0f, y0f, wx1, wy1}.
__device__ __forceinline__ float sample_lds(const float* lds, float4 p) {
    int x0 = (int)p.x, y0 = (int)p.y;     // floor values, may be -1
    int x1 = x0 + 1, y1 = y0 + 1;
    float wx1 = p.z, wy1 = p.w;
    float wx0 = 1.f - wx1, wy0 = 1.f - wy1;
    bool xv0 = (x0 >= 0) & (x0 < HW_W);
    bool xv1 = (x1 >= 0) & (x1 < HW_W);
    bool yv0 = (y0 >= 0) & (y0 < HW_H);
    bool yv1 = (y1 >= 0) & (y1 < HW_H);
    float v00 = (xv0 && yv0) ? lds[y0 * HW_W + x0] : 0.f;
    float v10 = (xv1 && yv0) ? lds[y0 * HW_W + x1] : 0.f;
    float v01 = (xv0 && yv1) ? lds[y1 * HW_W + x0] : 0.f;
    float v11 = (xv1 && yv1) ? lds[y1 * HW_W + x1] : 0.f;
    return v00 * wx0 * wy0 + v10 * wx1 * wy0 + v01 * wx0 * wy1 + v11 * wx1 * wy1;
}

// ---------- kernel 1: per-point bilinear setup ----------
__global__ void kprep(const float* __restrict__ coords, float4* __restrict__ pts, int P) {
    int i = blockIdx.x * 256 + threadIdx.x;
    if (i >= P) return;
    float cx = coords[2 * i], cy = coords[2 * i + 1];
    float x = cx * (float)HW_W - 0.5f;   // == ((2cx-1+1)*W - 1)*0.5
    float y = cy * (float)HW_H - 0.5f;
    float x0 = floorf(x), y0 = floorf(y);
    pts[i] = make_float4(x0, y0, x - x0, y - y0);
}

// ---------- kernel 2: sample tgt_masks -> t_samp[T][P] (bf16) + t_sum partials ----------
__global__ void ktgt(const float* __restrict__ tmasks, const float4* __restrict__ pts,
                     unsigned short* __restrict__ tsamp, float* __restrict__ tsum_part,
                     const int* __restrict__ lvl, int T, int P, int PS_CHUNK) {
    if (*lvl >= 2) return;
    __shared__ float lds[MASK_ELEMS];
    int t = blockIdx.x, ps = blockIdx.y, tid = threadIdx.x;
    const float* m = tmasks + (size_t)t * MASK_ELEMS;
    #pragma unroll
    for (int j = 0; j < MASK_ELEMS / 1024; ++j) {
        int o = j * 1024 + tid * 4;
        *(float4*)&lds[o] = *(const float4*)&m[o];
    }
    __syncthreads();
    float sum = 0.f;
    int pbeg = ps * PS_CHUNK, pend = min(P, pbeg + PS_CHUNK);
    for (int i = pbeg + tid; i < pend; i += 256) {
        float v = sample_lds(lds, pts[i]);
        tsamp[(size_t)t * P + i] = f2bf(v);
        sum += v;
    }
    __syncthreads();
    lds[tid] = sum;
    __syncthreads();
    for (int s = 128; s > 0; s >>= 1) {
        if (tid < s) lds[tid] += lds[tid + s];
        __syncthreads();
    }
    if (tid == 0) tsum_part[ps * T + t] = lds[0];
}

// ---------- kernel 3: sample pred_seg_mask -> s = sigmoid(.) -> S[N][P] (bf16) + s_sum ----------
__global__ void ksamp(const float* __restrict__ pmask, const float4* __restrict__ pts,
                      unsigned short* __restrict__ S, float* __restrict__ ssum,
                      const int* __restrict__ lvl, int P) {
    if (*lvl >= 2) return;
    __shared__ float lds[MASK_ELEMS];
    int n = blockIdx.x, tid = threadIdx.x;
    const float* m = pmask + (size_t)n * MASK_ELEMS;
    #pragma unroll
    for (int j = 0; j < MASK_ELEMS / 1024; ++j) {
        int o = j * 1024 + tid * 4;
        *(float4*)&lds[o] = *(const float4*)&m[o];
    }
    __syncthreads();
    float sum = 0.f;
    for (int i = tid; i < P; i += 256) {
        float v = sample_lds(lds, pts[i]);
        float s = 1.f / (1.f + __expf(-v));
        S[(size_t)n * P + i] = f2bf(s);
        sum += s;
    }
    __syncthreads();
    lds[tid] = sum;
    __syncthreads();
    for (int s = 128; s > 0; s >>= 1) {
        if (tid < s) lds[tid] += lds[tid + s];
        __syncthreads();
    }
    if (tid == 0) ssum[n] = lds[0];
}

// ---------- kernel 4: dot[n,t] partials over K-split (VALU f32 GEMM) ----------
__global__ __launch_bounds__(256) void kgemm(const unsigned short* __restrict__ S,
                                             const unsigned short* __restrict__ tsamp,
                                             float* __restrict__ Cpart,
                                             const int* __restrict__ lvl, int N, int P) {
    if (*lvl >= 2) return;
    __shared__ float sA[BM][BK + 2];    // +2 pad: bank-conflict-free, keeps float2 align
    __shared__ float sB[TT][BK + 2];
    int tid = threadIdx.x;
    int mt = blockIdx.x, ks = blockIdx.y;
    int n0 = mt * BM;
    int chunk = P / KSPLIT;             // 896
    int p0 = ks * chunk;
    int tx = tid & 31, ty = tid >> 5;   // tx: 5 t's each, ty: 4 n's each
    float acc[4][5];
    #pragma unroll
    for (int r = 0; r < 4; ++r)
        #pragma unroll
        for (int j = 0; j < 5; ++j) acc[r][j] = 0.f;

    for (int kk = 0; kk < chunk; kk += BK) {
        int pb = p0 + kk;
        __syncthreads();
        {   // stage A tile: 32x64 bf16 -> f32 LDS (one shot: 256 thr x 8)
            int row = tid >> 3, c8 = (tid & 7) << 3;
            ushortx8 v = *(const ushortx8*)&S[(size_t)(n0 + row) * P + pb + c8];
            #pragma unroll
            for (int j = 0; j < 8; ++j) sA[row][c8 + j] = bf2f(v[j]);
        }
        // stage B tile: 160x64 bf16 -> f32 LDS
        for (int i = tid; i < TT * 8; i += 256) {
            int row = i >> 3, c8 = (i & 7) << 3;
            ushortx8 v = *(const ushortx8*)&tsamp[(size_t)row * P + pb + c8];
            #pragma unroll
            for (int j = 0; j < 8; ++j) sB[row][c8 + j] = bf2f(v[j]);
        }
        __syncthreads();
        #pragma unroll 8
        for (int k = 0; k < BK; k += 2) {
            float2 a[4];
            #pragma unroll
            for (int r = 0; r < 4; ++r) a[r] = *(const float2*)&sA[ty * 4 + r][k];
            #pragma unroll
            for (int j = 0; j < 5; ++j) {
                float2 b = *(const float2*)&sB[tx * 5 + j][k];
                #pragma unroll
                for (int r = 0; r < 4; ++r) acc[r][j] += a[r].x * b.x + a[r].y * b.y;
            }
        }
    }
    size_t base = (size_t)ks * N * TT;
    #pragma unroll
    for (int r = 0; r < 4; ++r) {
        int n = n0 + ty * 4 + r;
        #pragma unroll
        for (int j = 0; j < 5; ++j)
            Cpart[base + (size_t)n * TT + tx * 5 + j] = acc[r][j];
    }
}

// ---------- kernel 5: epilogue — class + kpts + dice combine ----------
__global__ void kfinal(const float* __restrict__ logits, const float* __restrict__ opts,
                       const float* __restrict__ tpts, const float* __restrict__ Cpart,
                       const float* __restrict__ ssum, const float* __restrict__ tsum_part,
                       const int* __restrict__ lvl, float* __restrict__ out, int N, int T) {
    int idx = blockIdx.x * 256 + threadIdx.x;
    if (idx >= N * T) return;
    int n = idx / T, t = idx - n * T;

    float lg = logits[n];
    float p = 1.f / (1.f + __expf(-lg));
    float pos = 0.25f * (1.f - p) * (1.f - p) * (-logf(p + 1e-8f));
    float neg = 0.75f * p * p * (-logf(1.f - p + 1e-8f));
    float ccls = pos - neg;

    float kp = 0.f;
    const float4* a4 = (const float4*)(opts + (size_t)n * 32);
    const float4* b4 = (const float4*)(tpts + (size_t)t * 32);
    #pragma unroll
    for (int j = 0; j < 8; ++j) {
        float4 a = a4[j], b = b4[j];
        kp += fabsf(a.x - b.x) + fabsf(a.y - b.y) + fabsf(a.z - b.z) + fabsf(a.w - b.w);
    }

    float dice = 0.f;
    if (*lvl < 2) {
        float dot = 0.f;
        #pragma unroll
        for (int ks = 0; ks < KSPLIT; ++ks) dot += Cpart[((size_t)ks * N + n) * T + t];
        float ts = 0.f;
        #pragma unroll
        for (int ps = 0; ps < 4; ++ps) ts += tsum_part[ps * T + t];
        dice = 1.f - (2.f * dot + 1.f) / (ssum[n] + ts + 1.f);
    }
    out[idx] = 2.f * ccls + 5.f * kp + 5.f * dice;
}

extern "C" void kernel_launch(void* const* d_in, const int* in_sizes, int n_in,
                              void* d_out, int out_size, void* d_ws, size_t ws_size,
                              hipStream_t stream) {
    const float* logits = (const float*)d_in[0];
    const float* cpts   = (const float*)d_in[1];
    const float* pmask  = (const float*)d_in[2];
    const float* tpts   = (const float*)d_in[3];
    const float* tmasks = (const float*)d_in[4];
    const float* coords = (const float*)d_in[5];
    const int*   lvl    = (const int*)d_in[6];
    float* out = (float*)d_out;

    int N = in_sizes[0];        // bs*Q = 2400
    int T = in_sizes[3] / 32;   // 160
    int P = in_sizes[5] / 2;    // 12544

    char* w = (char*)d_ws;
    auto alloc = [&](size_t bytes) {
        char* r = w;
        w += (bytes + 255) & ~(size_t)255;
        return r;
    };
    float4*         pts    = (float4*)alloc((size_t)P * sizeof(float4));
    unsigned short* tsamp  = (unsigned short*)alloc((size_t)T * P * 2);
    unsigned short* S      = (unsigned short*)alloc((size_t)N * P * 2);
    float*          Cpart  = (float*)alloc((size_t)KSPLIT * N * T * 4);
    float*          ssumb  = (float*)alloc((size_t)N * 4);
    float*          tsum_p = (float*)alloc((size_t)4 * T * 4);

    kprep<<<(P + 255) / 256, 256, 0, stream>>>(coords, pts, P);
    int PS_CHUNK = (P + 3) / 4;
    ktgt<<<dim3(T, 4), 256, 0, stream>>>(tmasks, pts, tsamp, tsum_p, lvl, T, P, PS_CHUNK);
    ksamp<<<N, 256, 0, stream>>>(pmask, pts, S, ssumb, lvl, P);
    kgemm<<<dim3(N / BM, KSPLIT), 256, 0, stream>>>(S, tsamp, Cpart, lvl, N, P);
    kfinal<<<(N * T + 255) / 256, 256, 0, stream>>>(logits, cpts, tpts, Cpart, ssumb, tsum_p,
                                                    lvl, out, N, T);
}

// Round 2
// 193.275 us; speedup vs baseline: 2.1322x; 2.1322x over previous
//
#include <hip/hip_runtime.h>
#include <hip/hip_bf16.h>
#include <cstdint>

#define HW 128
#define MASK_ELEMS (HW * HW)

typedef unsigned short ushort_t;
typedef __attribute__((ext_vector_type(8))) short short8;
typedef __attribute__((ext_vector_type(4))) float f32x4;

__device__ __forceinline__ ushort_t f2bf(float f) {
    union { float f; unsigned int i; } c;
    c.f = f;
    unsigned int r = c.i + 0x7FFFu + ((c.i >> 16) & 1u);  // RNE
    return (ushort_t)(r >> 16);
}

// ---------- kernel 1: per-point bilinear setup -> base idx + validity-folded weights ----------
// Taps are always lds[b], lds[b+1], lds[b+128], lds[b+129] with b chosen so all 4 stay
// inside [0, 16384) (edge cases remap the window and swap the weight to the other slot,
// whose weight is provably 0 there).
__global__ void kprep(const float* __restrict__ coords, int* __restrict__ idx,
                      float4* __restrict__ wts, int P) {
    int i = blockIdx.x * 256 + threadIdx.x;
    if (i >= P) return;
    float cx = coords[2 * i], cy = coords[2 * i + 1];
    float x = cx * (float)HW - 0.5f;
    float y = cy * (float)HW - 0.5f;
    float x0f = floorf(x), y0f = floorf(y);
    float wx1 = x - x0f, wy1 = y - y0f;
    float wx0 = 1.f - wx1, wy0 = 1.f - wy1;
    int x0 = (int)x0f, y0 = (int)y0f;

    float wxA = (x0 >= 0) ? wx0 : wx1;            // x0==-1: only tap x=0 (weight wx1)
    float wxB = (x0 >= 0 && x0 < HW - 1) ? wx1 : 0.f;
    float wyA = (y0 >= 0) ? wy0 : wy1;
    float wyB = (y0 >= 0 && y0 < HW - 1) ? wy1 : 0.f;
    int bx = max(x0, 0), by = max(y0, 0);
    if (bx > HW - 2) { bx = HW - 2; wxB = wxA; wxA = 0.f; }  // keep b+1 in-row
    if (by > HW - 2) { by = HW - 2; wyB = wyA; wyA = 0.f; }  // keep b+129 in-tile

    idx[i] = by * HW + bx;
    wts[i] = make_float4(wxA * wyA, wxB * wyA, wxA * wyB, wxB * wyB);
}

// ---------- kernel 2: sample masks -> bf16 samples + row sums ----------
// DO_SIG=1: s = sigmoid(sample) (pred path). DO_SIG=0: raw sample (target path).
template <int DO_SIG>
__global__ __launch_bounds__(256) void ksample(const float* __restrict__ masks,
                                               const int* __restrict__ idx,
                                               const float4* __restrict__ wts,
                                               ushort_t* __restrict__ samp,
                                               float* __restrict__ sum_out,
                                               const int* __restrict__ lvl, int P, int R) {
    if (*lvl >= 2) return;
    __shared__ float lds[MASK_ELEMS];  // exactly 64 KB
    int r = blockIdx.x, tid = threadIdx.x;
    const float* m = masks + (size_t)r * MASK_ELEMS;
    #pragma unroll
    for (int j = 0; j < MASK_ELEMS / 1024; ++j) {
        int o = j * 1024 + tid * 4;
        *(float4*)&lds[o] = *(const float4*)&m[o];
    }
    __syncthreads();
    int chunk = P / gridDim.y;
    int pbeg = blockIdx.y * chunk;
    int pend = min(P, pbeg + chunk);
    float sum = 0.f;
    for (int i = pbeg + tid; i < pend; i += 256) {
        int b = idx[i];
        float4 w = wts[i];
        float v = w.x * lds[b] + w.y * lds[b + 1] + w.z * lds[b + HW] + w.w * lds[b + HW + 1];
        if (DO_SIG) v = __builtin_amdgcn_rcpf(1.f + __expf(-v));
        samp[(size_t)r * P + i] = f2bf(v);
        sum += v;
    }
    __syncthreads();
    lds[tid] = sum;
    __syncthreads();
    for (int s2 = 128; s2 > 0; s2 >>= 1) {
        if (tid < s2) lds[tid] += lds[tid + s2];
        __syncthreads();
    }
    if (tid == 0) sum_out[blockIdx.y * R + r] = lds[0];
}

// ---------- kernel 3: MFMA split-K GEMM: Cpart[ks][n][t] = sum_k S[n,k]*Tm[t,k] ----------
// No LDS: fragments loaded straight from global (16B/lane, L1/L2 amortize the 2x wave reuse).
// A and B frags use the SAME lane->k mapping, so the reduction is layout-permutation-proof.
#define LDF(Aarr, Barr, kof)                                                              \
    do {                                                                                  \
        _Pragma("unroll") for (int m_ = 0; m_ < 3; ++m_)                                  \
            Aarr[m_] = *(const short8*)(pa + (size_t)m_ * 16 * P + (kof));                \
        _Pragma("unroll") for (int j_ = 0; j_ < 5; ++j_)                                  \
            Barr[j_] = *(const short8*)(pb + (size_t)j_ * 16 * P + (kof));                \
    } while (0)

#define FMAS(Aarr, Barr)                                                                  \
    do {                                                                                  \
        _Pragma("unroll") for (int m_ = 0; m_ < 3; ++m_) {                                \
            _Pragma("unroll") for (int j_ = 0; j_ < 5; ++j_)                              \
                acc[m_][j_] = __builtin_amdgcn_mfma_f32_16x16x32_bf16(                    \
                    Aarr[m_], Barr[j_], acc[m_][j_], 0, 0, 0);                            \
        }                                                                                 \
    } while (0)

__global__ __launch_bounds__(256) void kgemm(const ushort_t* __restrict__ S,
                                             const ushort_t* __restrict__ Tm,
                                             float* __restrict__ Cpart,
                                             const int* __restrict__ lvl,
                                             int N, int T, int P, int nsteps) {
    if (*lvl >= 2) return;
    int tid = threadIdx.x;
    int wid = tid >> 6, lane = tid & 63;
    int wm = wid >> 1, wt = wid & 1;
    int r = lane & 15, g = lane >> 4;
    int n0 = blockIdx.x * 96 + wm * 48;
    int t0 = wt * 80;
    size_t k0 = (size_t)blockIdx.y * nsteps * 32 + g * 8;
    const ushort_t* pa = S + (size_t)(n0 + r) * P + k0;
    const ushort_t* pb = Tm + (size_t)(t0 + r) * P + k0;

    f32x4 acc[3][5];
    #pragma unroll
    for (int m2 = 0; m2 < 3; ++m2)
        #pragma unroll
        for (int j2 = 0; j2 < 5; ++j2) acc[m2][j2] = (f32x4){0.f, 0.f, 0.f, 0.f};

    short8 a0[3], b0[5], a1[3], b1[5];
    LDF(a0, b0, 0);
    int ks = 0;
    for (; ks + 2 < nsteps; ks += 2) {  // nsteps is even
        LDF(a1, b1, (ks + 1) * 32);
        FMAS(a0, b0);
        LDF(a0, b0, (ks + 2) * 32);
        FMAS(a1, b1);
    }
    LDF(a1, b1, (ks + 1) * 32);
    FMAS(a0, b0);
    FMAS(a1, b1);

    size_t cb = (size_t)blockIdx.y * N * T;
    #pragma unroll
    for (int m2 = 0; m2 < 3; ++m2)
        #pragma unroll
        for (int j2 = 0; j2 < 5; ++j2)
            #pragma unroll
            for (int q = 0; q < 4; ++q) {
                int row = n0 + m2 * 16 + g * 4 + q;   // C/D: row=(lane>>4)*4+reg
                int col = t0 + j2 * 16 + r;           //      col=lane&15
                Cpart[cb + (size_t)row * T + col] = acc[m2][j2][q];
            }
}

// ---------- kernel 4: epilogue — class + kpts + dice combine ----------
__global__ void kfinal(const float* __restrict__ logits, const float* __restrict__ opts,
                       const float* __restrict__ tpts, const float* __restrict__ Cpart,
                       const float* __restrict__ ssum, const float* __restrict__ tsum2,
                       const int* __restrict__ lvl, float* __restrict__ out,
                       int N, int T, int nks) {
    int idx = blockIdx.x * 256 + threadIdx.x;
    if (idx >= N * T) return;
    int n = idx / T, t = idx - n * T;

    float lg = logits[n];
    float p = 1.f / (1.f + __expf(-lg));
    float pos = 0.25f * (1.f - p) * (1.f - p) * (-logf(p + 1e-8f));
    float neg = 0.75f * p * p * (-logf(1.f - p + 1e-8f));
    float ccls = pos - neg;

    float kp = 0.f;
    const float4* a4 = (const float4*)(opts + (size_t)n * 32);
    const float4* b4 = (const float4*)(tpts + (size_t)t * 32);
    #pragma unroll
    for (int j = 0; j < 8; ++j) {
        float4 a = a4[j], b = b4[j];
        kp += fabsf(a.x - b.x) + fabsf(a.y - b.y) + fabsf(a.z - b.z) + fabsf(a.w - b.w);
    }

    float dice = 0.f;
    if (*lvl < 2) {
        float dot = 0.f;
        for (int ks = 0; ks < nks; ++ks) dot += Cpart[(size_t)ks * N * T + idx];
        float ts = tsum2[t] + tsum2[T + t];
        dice = 1.f - (2.f * dot + 1.f) / (ssum[n] + ts + 1.f);
    }
    out[idx] = 2.f * ccls + 5.f * kp + 5.f * dice;
}

extern "C" void kernel_launch(void* const* d_in, const int* in_sizes, int n_in,
                              void* d_out, int out_size, void* d_ws, size_t ws_size,
                              hipStream_t stream) {
    const float* logits = (const float*)d_in[0];
    const float* cpts   = (const float*)d_in[1];
    const float* pmask  = (const float*)d_in[2];
    const float* tpts   = (const float*)d_in[3];
    const float* tmasks = (const float*)d_in[4];
    const float* coords = (const float*)d_in[5];
    const int*   lvl    = (const int*)d_in[6];
    float* out = (float*)d_out;

    int N = in_sizes[0];        // 2400
    int T = in_sizes[3] / 32;   // 160
    int P = in_sizes[5] / 2;    // 12544

    char* w = (char*)d_ws;
    auto alloc = [&](size_t bytes) {
        char* r = w;
        w += (bytes + 255) & ~(size_t)255;
        return r;
    };
    int*      idxb  = (int*)alloc((size_t)P * 4);
    float4*   wtsb  = (float4*)alloc((size_t)P * 16);
    ushort_t* tsamp = (ushort_t*)alloc((size_t)T * P * 2);
    ushort_t* S     = (ushort_t*)alloc((size_t)N * P * 2);
    float*    ssumb = (float*)alloc((size_t)N * 4);
    float*    tsum2 = (float*)alloc((size_t)2 * T * 4);
    size_t base_bytes = (size_t)(w - (char*)d_ws);

    // split-K: pick the largest of {28,14,7} whose Cpart fits the workspace
    // (all divide P/32=392; 28/14 give even step counts, 7 gives 56 — also even)
    int nks = 28;
    if (base_bytes + (size_t)nks * N * T * 4 > ws_size) nks = 14;
    if (base_bytes + (size_t)nks * N * T * 4 > ws_size) nks = 7;
    int nsteps = (P / 32) / nks;
    float* Cpart = (float*)alloc((size_t)nks * N * T * 4);

    kprep<<<(P + 255) / 256, 256, 0, stream>>>(coords, idxb, wtsb, P);
    ksample<0><<<dim3(T, 2), 256, 0, stream>>>(tmasks, idxb, wtsb, tsamp, tsum2, lvl, P, T);
    ksample<1><<<dim3(N, 1), 256, 0, stream>>>(pmask, idxb, wtsb, S, ssumb, lvl, P, N);
    kgemm<<<dim3(N / 96, nks), 256, 0, stream>>>(S, tsamp, Cpart, lvl, N, T, P, nsteps);
    kfinal<<<(N * T + 255) / 256, 256, 0, stream>>>(logits, cpts, tpts, Cpart, ssumb, tsum2,
                                                    lvl, out, N, T, nks);
}